// Round 14
// baseline (17806.125 us; speedup 1.0000x reference)
//
#include <hip/hip_runtime.h>
#include <type_traits>

#define HD 64
#define WD 64
#define HW 4096
#define BATCH 2
#define NSLOT 4   // (branch, batch) merged slots: s = br*2 + b

typedef double v4d __attribute__((ext_vector_type(4)));
typedef double d2t __attribute__((ext_vector_type(2)));
typedef d2t d2u __attribute__((aligned(8)));      // unaligned-capable double2
typedef float f2t __attribute__((ext_vector_type(2)));
typedef f2t f2u __attribute__((aligned(4)));      // unaligned-capable float2

// ---- packed A-operand tables for MFMA waves, BOTH candidate layouts ----
__global__ void pack_a_def_k(const float* __restrict__ w0, const float* __restrict__ w1,
                             const float* __restrict__ w2, float* __restrict__ pa) {
    int idx = blockIdx.x * 256 + threadIdx.x;
    if (idx >= 2 * 3 * 4 * 576 * 64 * 4) return;
    int tl = idx & 3;
    int l  = (idx >> 2) & 63;
    int m  = (idx >> 8) % 576;
    int rest = (idx >> 8) / 576;     // (L*3+conv)*4+wv
    int wv = rest & 3;
    int Lc = rest >> 2;
    int conv = Lc % 3, L = Lc / 3;
    int a_i = L ? (l >> 2) : (l & 15);
    int a_k = L ? (l & 3)  : (l >> 4);
    int kk = 4 * m + a_k;
    int c = kk / 9, k = kk % 9;
    int o = wv * 64 + tl * 16 + a_i;
    const float* w = (conv == 0) ? w0 : (conv == 1) ? w1 : w2;
    pa[idx] = w[((size_t)o * 256 + c) * 9 + k];
}

__global__ void pack_a_pred_k(const float* __restrict__ w, float* __restrict__ pa) {
    int idx = blockIdx.x * 256 + threadIdx.x;
    if (idx >= 2 * 2 * 288 * 64 * 4) return;
    int tl = idx & 3;
    int l  = (idx >> 2) & 63;
    int m  = (idx >> 8) % 288;
    int rest = (idx >> 8) / 288;     // L*2+wv
    int wv = rest & 1, L = rest >> 1;
    int a_i = L ? (l >> 2) : (l & 15);
    int a_k = L ? (l & 3)  : (l >> 4);
    int kk = 4 * m + a_k;
    int c = kk / 9, k = kk % 9;
    int o = wv * 64 + tl * 16 + a_i;
    pa[idx] = w[((size_t)o * 128 + c) * 9 + k];
}

// ---- B-layout weight tables for VALU waves: wt[(c*9+k)*O + o] ----
__global__ void transpose_w3_k(const float* __restrict__ w0, const float* __restrict__ w1,
                               const float* __restrict__ w2, float* __restrict__ wt) {
    const int N = 256 * 256 * 9;
    int idx = blockIdx.x * 256 + threadIdx.x;
    if (idx >= 3 * N) return;
    int which = idx / N, r = idx % N;
    const float* w = (which == 0) ? w0 : (which == 1) ? w1 : w2;
    int k = r % 9;
    int c = (r / 9) % 256;
    int o = r / (9 * 256);
    wt[(size_t)which * N + (size_t)(c * 9 + k) * 256 + o] = w[r];
}

__global__ void transpose_wp_k(const float* __restrict__ w, float* __restrict__ wt) {
    int idx = blockIdx.x * 256 + threadIdx.x;
    if (idx >= 128 * 128 * 9) return;
    int k = idx % 9;
    int c = (idx / 9) % 128;
    int o = idx / (9 * 128);
    wt[(size_t)(c * 9 + k) * 128 + o] = w[idx];
}

// ---- merged offset-weight transpose: w[o][c][kk] -> owt[which][c][kk][20] ---
__global__ void transpose_ow4_k(const float* __restrict__ w0, const float* __restrict__ w1,
                                const float* __restrict__ w2, const float* __restrict__ w3,
                                float* __restrict__ owt) {
    const int N = 256 * 180;
    int idx = blockIdx.x * 256 + threadIdx.x;
    if (idx >= 4 * N) return;
    int which = idx / N, r = idx % N;
    const float* w = (which == 0) ? w0 : (which == 1) ? w1 : (which == 2) ? w2 : w3;
    int k20 = r % 20;
    int kk  = (r / 20) % 9;
    int c   = r / 180;
    owt[idx] = (k20 < 18) ? w[((size_t)k20 * 256 + c) * 9 + kk] : 0.f;
}

// ---- pack 4 slots: slot s=br*2+b, c<128 -> img 2b+br ; c>=128 -> img 2b+1 ---
__global__ void pack_feat4_d(const float* __restrict__ in, double* __restrict__ dst) {
    int idx = blockIdx.x * 256 + threadIdx.x;
    if (idx >= NSLOT * 256 * HW) return;
    int i = idx % HW;
    int c = (idx / HW) & 255;
    int s = idx / (256 * HW);
    int b = s & 1, br = s >> 1;
    int img = (c < 128) ? (2 * b + br) : (2 * b + 1);
    dst[idx] = (double)in[((size_t)(img * 128 + (c & 127))) * HW + i];
}

// ---- runtime-probe the f64 MFMA fragment layout ----
__device__ __forceinline__ void probe_mfma_f64(
    int lane, int& aL1, int& b_k, int& b_j, int row_map[4], int col_map[4]) {
    v4d z = {0.0, 0.0, 0.0, 0.0};
    v4d pA = __builtin_amdgcn_mfma_f64_16x16x4f64((double)lane, 1.0, z, 0, 0, 0);
    v4d pB = __builtin_amdgcn_mfma_f64_16x16x4f64(1.0, (double)lane, z, 0, 0, 0);
    int vA = (int)pA[0];
    aL1 = ((vA & 3) != 0);
    int vB = (int)pB[0];
    if ((vB & 3) == 0) { b_j = lane & 15; b_k = lane >> 4; }
    else               { b_j = lane >> 2; b_k = lane & 3; }
#pragma unroll
    for (int r = 0; r < 4; ++r) {
        int va = (int)pA[r];
        row_map[r] = ((va & 3) == 0) ? (va - 96) >> 2 : (va - 6) >> 4;
        int vb = (int)pB[r];
        col_map[r] = ((vb & 3) == 0) ? (vb - 96) >> 2 : (vb - 6) >> 4;
    }
}

// ---------------- FUSED offset-conv + deformable GEMM, dual-pipe -------------
// Grid (4, HD, NSLOT); block O threads (O/64 waves). Lower-half waves GEMM via
// f64 MFMA (matrix pipe, o lower half); upper-half waves GEMM via f64 vector
// FMA register tile (VALU pipe, o upper half). Shared staging/phases.
template <int O, int CC, bool PRED>
__global__ __launch_bounds__(O) void fused_deform_d(
    const double* __restrict__ csrc,            // (NSLOT,256,HW) offset source
    const float*  __restrict__ owt,             // [c][kk][20]
    const float*  __restrict__ fsrc,            // raw inputs (PRED only)
    const float4* __restrict__ pa,              // packed A (MFMA), layout0 base
    int paL1off,                                // float4 units to layout1
    const float*  __restrict__ wt,              // [(c*9+k)*O + o] (VALU)
    double* __restrict__ dst, int Ci) {
    constexpr int NCGT = O / 16;
    constexpr int CPG  = 256 / NCGT;
    constexpr int KC   = CC * 9;
    constexpr int NELEM = CC * 144;
    constexpr int NR   = NELEM / O;
    constexpr int REM  = NELEM % O;
    constexpr int NG   = CC;
    constexpr int NW   = O / 64;     // waves per block
    static_assert(2 * KC * 17 >= NG * 288, "phase-0 scratch");
    static_assert(NCGT % NG == 0, "phase-0 rounds");
    static_assert(KC % 4 == 0, "K steps");
    static_assert(NW % 2 == 0, "wave split");

    int px0 = blockIdx.x * 16;
    int h   = blockIdx.y;
    int s   = blockIdx.z;
    int t   = threadIdx.x;

    __shared__ double s_samp[2][KC * 17];       // dbuf; also ph0 scratch
    __shared__ int    s_addr2[9][16][2];        // row bases (element offsets)
    __shared__ double s_w4[9][16][4];           // {cax, cay, wy0v, wy1v}
    __shared__ double s_off[18][16];

    // ---- phase 0: offset conv ----
    {
        int px = t & 15, cg = t >> 4;
        int gx = px0 + px;
        double part[18];
#pragma unroll
        for (int k = 0; k < 18; ++k) part[k] = 0.0;
        const double* fb = csrc + (size_t)s * 256 * HW;
        bool ym = (h > 0), yp = (h < HD - 1), xm = (gx > 0), xp = (gx < WD - 1);
        for (int cc = 0; cc < CPG; ++cc) {
            int c = cg * CPG + cc;
            const double* fc = fb + (size_t)c * HW + h * WD + gx;
            double v[9];
            v[0] = (ym && xm) ? fc[-WD - 1] : 0.0;
            v[1] = ym ? fc[-WD] : 0.0;
            v[2] = (ym && xp) ? fc[-WD + 1] : 0.0;
            v[3] = xm ? fc[-1] : 0.0;
            v[4] = fc[0];
            v[5] = xp ? fc[1] : 0.0;
            v[6] = (yp && xm) ? fc[WD - 1] : 0.0;
            v[7] = yp ? fc[WD] : 0.0;
            v[8] = (yp && xp) ? fc[WD + 1] : 0.0;
            const float* wr = owt + (size_t)c * 180;
#pragma unroll
            for (int kk = 0; kk < 9; ++kk) {
                float wl[20];
                ((float4*)wl)[0] = *(const float4*)(wr + kk * 20);
                ((float4*)wl)[1] = *(const float4*)(wr + kk * 20 + 4);
                ((float4*)wl)[2] = *(const float4*)(wr + kk * 20 + 8);
                ((float4*)wl)[3] = *(const float4*)(wr + kk * 20 + 12);
                ((float4*)wl)[4] = *(const float4*)(wr + kk * 20 + 16);
                double vv = v[kk];
#pragma unroll
                for (int k = 0; k < 18; ++k)
                    part[k] = fma(vv, (double)wl[k], part[k]);
            }
        }
        double* s_part = &s_samp[0][0];
        for (int r0 = 0; r0 < NCGT; r0 += NG) {
            if (cg >= r0 && cg < r0 + NG) {
#pragma unroll
                for (int k = 0; k < 18; ++k)
                    s_part[((size_t)(cg - r0) * 18 + k) * 16 + px] = part[k];
            }
            __syncthreads();
            for (int i = t; i < 288; i += O) {
                int k = i >> 4, p2 = i & 15;
                double ssum = 0.0;
                for (int g = 0; g < NG; ++g)
                    ssum += s_part[((size_t)g * 18 + k) * 16 + p2];
                if (r0 == 0) s_off[k][p2] = ssum;
                else         s_off[k][p2] += ssum;
            }
            __syncthreads();
        }
    }

    // ---- phase 1: sampling positions -> paired-row bases + eff. weights ----
    for (int i = t; i < 144; i += O) {
        int k = i / 16, px = i % 16, wc = px0 + px;
        double dy = s_off[2 * k][px];
        double dx = s_off[2 * k + 1][px];
        double py  = dy + (double)(k / 3 - 1 + h);
        double pxf = dx + (double)(k % 3 - 1 + wc);
        double y0f = floor(py), x0f = floor(pxf);
        double wy1 = py - y0f, wx1 = pxf - x0f;
        double wy0 = 1.0 - wy1, wx0 = 1.0 - wx1;
        double y0c = fmax(-2.0, fmin(66.0, y0f));
        double x0c = fmax(-2.0, fmin(66.0, x0f));
        int y0 = (int)y0c, x0 = (int)x0c;
        int y1 = y0 + 1,   x1 = x0 + 1;
        bool vy0 = (y0 >= 0 && y0 < HD), vy1 = (y1 >= 0 && y1 < HD);
        bool vx0 = (x0 >= 0 && x0 < WD), vx1 = (x1 >= 0 && x1 < WD);
        int yc0 = min(max(y0, 0), HD - 1), yc1 = min(max(y1, 0), HD - 1);
        int xbase = min(max(x0, 0), WD - 2);
        s_addr2[k][px][0] = yc0 * WD + xbase;
        s_addr2[k][px][1] = yc1 * WD + xbase;
        bool sel0 = (x0 >= WD - 1);   // corner x0 uses .y
        bool sel1 = (x0 >= 0);        // corner x1 uses .y
        double wx0v = vx0 ? wx0 : 0.0;
        double wx1v = vx1 ? wx1 : 0.0;
        s_w4[k][px][0] = (sel0 ? 0.0 : wx0v) + (sel1 ? 0.0 : wx1v);  // cax
        s_w4[k][px][1] = (sel0 ? wx0v : 0.0) + (sel1 ? wx1v : 0.0);  // cay
        s_w4[k][px][2] = vy0 ? wy0 : 0.0;
        s_w4[k][px][3] = vy1 ? wy1 : 0.0;
    }
    __syncthreads();

    // ---- phase 2: dbuf paired staging + dual-pipe GEMM ---------------------
    int b = s & 1, br = s >> 1;
    const double* srcb_d = csrc + (size_t)s * 256 * HW;
    const float*  srcb_f = PRED ? (fsrc + (size_t)(2 * b + br) * 128 * HW) : nullptr;

    using PairT = typename std::conditional<PRED, f2u, d2u>::type;
    PairT rp0[NR + 1], rp1[NR + 1];

    auto stage_issue = [&](int c0) {
#pragma unroll
        for (int n = 0; n <= NR; ++n) {
            if (n == NR && (REM == 0 || t >= REM)) continue;
            int i = t + n * O;
            int px = i & 15, kk = (i >> 4) % 9, c = i / 144;
            int a0 = s_addr2[kk][px][0], a1 = s_addr2[kk][px][1];
            if constexpr (PRED) {
                const float* p = srcb_f + (size_t)(c0 + c) * HW;
                rp0[n] = *(const f2u*)(p + a0);
                rp1[n] = *(const f2u*)(p + a1);
            } else {
                const double* p = srcb_d + (size_t)(c0 + c) * HW;
                rp0[n] = *(const d2u*)(p + a0);
                rp1[n] = *(const d2u*)(p + a1);
            }
        }
    };
    auto stage_finish = [&](int buf) {
#pragma unroll
        for (int n = 0; n <= NR; ++n) {
            if (n == NR && (REM == 0 || t >= REM)) continue;
            int i = t + n * O;
            int px = i & 15, kk = (i >> 4) % 9, c = i / 144;
            const double* wq = s_w4[kk][px];
            double r0 = (double)rp0[n].x * wq[0] + (double)rp0[n].y * wq[1];
            double r1 = (double)rp1[n].x * wq[0] + (double)rp1[n].y * wq[1];
            s_samp[buf][(c * 9 + kk) * 17 + px] = wq[2] * r0 + wq[3] * r1;
        }
    };

    int lane = t & 63;
    int wvid = t >> 6;
    const bool isMfma = (wvid < NW / 2);
    const int nch = Ci / CC;

    if (isMfma) {
        // ================= MFMA waves: o in [wvid*64, wvid*64+64) ===========
        int aL1, b_k, b_j;
        int row_map[4], col_map[4];
        probe_mfma_f64(lane, aL1, b_k, b_j, row_map, col_map);

        size_t TOTM = (size_t)Ci * 9 / 4;
        const float4* wp0 = pa + (aL1 ? (size_t)paL1off : 0)
                          + (size_t)wvid * TOTM * 64 + lane;

        v4d acc[4];
#pragma unroll
        for (int tl = 0; tl < 4; ++tl) acc[tl] = (v4d){0.0, 0.0, 0.0, 0.0};

        stage_issue(0);
        stage_finish(0);
        __syncthreads();

        for (int ch = 0; ch < nch; ++ch) {
            int cur = ch & 1;
            bool more = (ch + 1 < nch);
            if (more) stage_issue((ch + 1) * CC);
            {
                const double* sb = &s_samp[cur][0];
                const float4* wp = wp0 + (size_t)ch * (KC / 4) * 64;
#pragma unroll
                for (int m = 0; m < KC / 4; ++m) {
                    float4 av = wp[(size_t)m * 64];
                    double bval = sb[(4 * m + b_k) * 17 + b_j];
                    acc[0] = __builtin_amdgcn_mfma_f64_16x16x4f64((double)av.x, bval, acc[0], 0, 0, 0);
                    acc[1] = __builtin_amdgcn_mfma_f64_16x16x4f64((double)av.y, bval, acc[1], 0, 0, 0);
                    acc[2] = __builtin_amdgcn_mfma_f64_16x16x4f64((double)av.z, bval, acc[2], 0, 0, 0);
                    acc[3] = __builtin_amdgcn_mfma_f64_16x16x4f64((double)av.w, bval, acc[3], 0, 0, 0);
                }
            }
            if (more) stage_finish(cur ^ 1);
            __syncthreads();
        }
        int o0w = wvid * 64;
#pragma unroll
        for (int tl = 0; tl < 4; ++tl) {
#pragma unroll
            for (int r = 0; r < 4; ++r) {
                int o = o0w + tl * 16 + row_map[r];
                dst[((size_t)(s * O + o) * HD + h) * WD + px0 + col_map[r]] = acc[tl][r];
            }
        }
    } else {
        // ================= VALU waves: o in [wvid*64, wvid*64+64) ===========
        int og = lane >> 2;           // 0..15 -> 4 o's each
        int pg = lane & 3;            // 0..3  -> 4 px each
        int obase = wvid * 64;

        double acc[4][4];
#pragma unroll
        for (int a = 0; a < 4; ++a)
#pragma unroll
            for (int p = 0; p < 4; ++p) acc[a][p] = 0.0;

        stage_issue(0);
        stage_finish(0);
        __syncthreads();

        const float* wrow = wt + obase + og * 4;
        for (int ch = 0; ch < nch; ++ch) {
            int cur = ch & 1;
            bool more = (ch + 1 < nch);
            if (more) stage_issue((ch + 1) * CC);
            {
                const double* sb = &s_samp[cur][0];
#pragma unroll
                for (int r = 0; r < KC; ++r) {
                    const float4 wv4 = *(const float4*)&wrow[(size_t)(ch * KC + r) * O];
                    const double* sp = sb + r * 17 + pg * 4;
                    double s0 = sp[0], s1 = sp[1], s2 = sp[2], s3 = sp[3];
                    double w0 = (double)wv4.x, w1 = (double)wv4.y,
                           w2 = (double)wv4.z, w3 = (double)wv4.w;
                    acc[0][0] = fma(w0, s0, acc[0][0]);
                    acc[0][1] = fma(w0, s1, acc[0][1]);
                    acc[0][2] = fma(w0, s2, acc[0][2]);
                    acc[0][3] = fma(w0, s3, acc[0][3]);
                    acc[1][0] = fma(w1, s0, acc[1][0]);
                    acc[1][1] = fma(w1, s1, acc[1][1]);
                    acc[1][2] = fma(w1, s2, acc[1][2]);
                    acc[1][3] = fma(w1, s3, acc[1][3]);
                    acc[2][0] = fma(w2, s0, acc[2][0]);
                    acc[2][1] = fma(w2, s1, acc[2][1]);
                    acc[2][2] = fma(w2, s2, acc[2][2]);
                    acc[2][3] = fma(w2, s3, acc[2][3]);
                    acc[3][0] = fma(w3, s0, acc[3][0]);
                    acc[3][1] = fma(w3, s1, acc[3][1]);
                    acc[3][2] = fma(w3, s2, acc[3][2]);
                    acc[3][3] = fma(w3, s3, acc[3][3]);
                }
            }
            if (more) stage_finish(cur ^ 1);
            __syncthreads();
        }
#pragma unroll
        for (int oi = 0; oi < 4; ++oi) {
            double* d = dst + ((size_t)(s * O + obase + og * 4 + oi) * HD + h) * WD
                      + px0 + pg * 4;
#pragma unroll
            for (int pi = 0; pi < 4; ++pi) d[pi] = acc[oi][pi];
        }
    }
}

// ---------------- S-net conv3x3: 4 outputs per thread, fp64 ------------------
__global__ __launch_bounds__(256) void conv3x3_s4_d(
    const double* __restrict__ src, const float* __restrict__ w,
    double* __restrict__ dst, int Ci, int O, int relu) {
    int idx = blockIdx.x * 256 + threadIdx.x;
    int px   = idx & 4095;
    int rest = idx >> 12;
    int og   = rest % (O >> 2);
    int img  = rest / (O >> 2);
    if (img >= NSLOT) return;
    int x = px & 63, h = px >> 6;
    const double* sb = src + (size_t)img * Ci * HW + h * WD + x;
    bool ym = (h > 0), yp = (h < HD - 1), xm = (x > 0), xp = (x < WD - 1);
    double acc[4] = {0.0, 0.0, 0.0, 0.0};
    for (int c = 0; c < Ci; ++c) {
        const double* sc = sb + (size_t)c * HW;
        double v[9];
        v[0] = (ym && xm) ? sc[-WD - 1] : 0.0;
        v[1] = ym ? sc[-WD] : 0.0;
        v[2] = (ym && xp) ? sc[-WD + 1] : 0.0;
        v[3] = xm ? sc[-1] : 0.0;
        v[4] = sc[0];
        v[5] = xp ? sc[1] : 0.0;
        v[6] = (yp && xm) ? sc[WD - 1] : 0.0;
        v[7] = yp ? sc[WD] : 0.0;
        v[8] = (yp && xp) ? sc[WD + 1] : 0.0;
#pragma unroll
        for (int oi = 0; oi < 4; ++oi) {
            const float* wc = w + ((size_t)(og * 4 + oi) * Ci + c) * 9;
#pragma unroll
            for (int k = 0; k < 9; ++k)
                acc[oi] = fma(v[k], (double)wc[k], acc[oi]);
        }
    }
#pragma unroll
    for (int oi = 0; oi < 4; ++oi) {
        double vv = acc[oi];
        if (relu) vv = fmax(vv, 0.0);
        dst[((size_t)(img * O + og * 4 + oi)) * HW + px] = vv;
    }
}

// ---------------- direct conv3x3 (final O=1 S-conv), 4 imgs ------------------
__global__ __launch_bounds__(256) void conv3x3_direct_d(
    const double* __restrict__ src, const float* __restrict__ w,
    double* __restrict__ dst, int Ci, int O, int relu) {
    int idx = blockIdx.x * 256 + threadIdx.x;
    int total = NSLOT * O * HW;
    if (idx >= total) return;
    int x = idx & (WD - 1);
    int h = (idx >> 6) & (HD - 1);
    int rest = idx >> 12;
    int o = rest % O;
    int img = rest / O;
    const double* s  = src + (size_t)img * Ci * HW + h * WD + x;
    const float*  wo = w + (size_t)o * Ci * 9;
    bool ym = (h > 0), yp = (h < HD - 1), xm = (x > 0), xp = (x < WD - 1);
    double a0 = 0.0, a1 = 0.0, a2 = 0.0;
    for (int c = 0; c < Ci; ++c) {
        const double* sc = s + (size_t)c * HW;
        const float*  wc = wo + c * 9;
        if (ym) {
            double v0 = xm ? sc[-WD - 1] : 0.0;
            double v1 = sc[-WD];
            double v2 = xp ? sc[-WD + 1] : 0.0;
            a0 = fma(v0, (double)wc[0], a0);
            a0 = fma(v1, (double)wc[1], a0);
            a0 = fma(v2, (double)wc[2], a0);
        }
        {
            double v0 = xm ? sc[-1] : 0.0;
            double v1 = sc[0];
            double v2 = xp ? sc[1] : 0.0;
            a1 = fma(v0, (double)wc[3], a1);
            a1 = fma(v1, (double)wc[4], a1);
            a1 = fma(v2, (double)wc[5], a1);
        }
        if (yp) {
            double v0 = xm ? sc[WD - 1] : 0.0;
            double v1 = sc[WD];
            double v2 = xp ? sc[WD + 1] : 0.0;
            a2 = fma(v0, (double)wc[6], a2);
            a2 = fma(v1, (double)wc[7], a2);
            a2 = fma(v2, (double)wc[8], a2);
        }
    }
    double acc = (a0 + a1) + a2;
    if (relu) acc = fmax(acc, 0.0);
    dst[idx] = acc;
}

// ---------------- fusion: cos-sim -> softmax -> blend, fp64 ------------------
__global__ void fuse_d(const double* __restrict__ dfm,   // (4,128,HW)
                       const double* __restrict__ wbuf,  // (4,HW)
                       float* __restrict__ out) {
    int idx = blockIdx.x * 256 + threadIdx.x;
    if (idx >= BATCH * 128 * HW) return;
    int i = idx % HW;
    int b = idx / (128 * HW);
    double a  = wbuf[(size_t)b * HW + i];
    double bb = wbuf[(size_t)(2 + b) * HW + i];
    double Wx = (a * bb) / sqrt(fmax((a * a) * (bb * bb), 1e-16));
    double Wy = (bb * bb) / sqrt(fmax((bb * bb) * (bb * bb), 1e-16));
    double m  = fmax(Wx, Wy);
    double e0 = exp(Wx - m), e1 = exp(Wy - m);
    double inv = 1.0 / (e0 + e1);
    double d0 = dfm[idx];
    double d1 = dfm[(size_t)2 * 128 * HW + idx];
    out[idx] = (float)((d0 * e0 + d1 * e1) * inv);
}

// ---------------- launch -----------------------------------------------------
extern "C" void kernel_launch(void* const* d_in, const int* in_sizes, int n_in,
                              void* d_out, int out_size, void* d_ws, size_t ws_size,
                              hipStream_t stream) {
    const float* inputs = (const float*)d_in[2];
    const float* off_w[4] = {(const float*)d_in[3], (const float*)d_in[4],
                             (const float*)d_in[5], (const float*)d_in[6]};
    const float* def_w[3] = {(const float*)d_in[7], (const float*)d_in[8],
                             (const float*)d_in[9]};
    const float* pred_w = (const float*)d_in[10];
    const float* s_w[3] = {(const float*)d_in[11], (const float*)d_in[12],
                           (const float*)d_in[13]};
    float* out = (float*)d_out;

    // workspace (double units; all sub-arrays even-double => 16B aligned)
    double* ws = (double*)d_ws;
    size_t o = 0;
    double* featA = ws + o; o += (size_t)NSLOT * 256 * HW;
    double* featB = ws + o; o += (size_t)NSLOT * 256 * HW;
    float* owt    = (float*)(ws + o); o += (size_t)4 * 256 * 180 / 2;
    float* paDef  = (float*)(ws + o); o += (size_t)2 * 3 * 589824 / 2;
    float* paPred = (float*)(ws + o); o += (size_t)2 * 147456 / 2;
    float* wtdef  = (float*)(ws + o); o += (size_t)3 * 589824 / 2;
    float* wtpred = (float*)(ws + o); o += (size_t)147456 / 2;
    if (ws_size < o * sizeof(double)) return;

    auto cdiv = [](int a, int b) { return (a + b - 1) / b; };

    pack_a_def_k<<<cdiv(2 * 3 * 589824, 256), 256, 0, stream>>>(
        def_w[0], def_w[1], def_w[2], paDef);
    pack_a_pred_k<<<cdiv(2 * 147456, 256), 256, 0, stream>>>(pred_w, paPred);
    transpose_w3_k<<<cdiv(3 * 589824, 256), 256, 0, stream>>>(
        def_w[0], def_w[1], def_w[2], wtdef);
    transpose_wp_k<<<cdiv(147456, 256), 256, 0, stream>>>(pred_w, wtpred);
    transpose_ow4_k<<<cdiv(4 * 256 * 180, 256), 256, 0, stream>>>(
        off_w[0], off_w[1], off_w[2], off_w[3], owt);

    pack_feat4_d<<<cdiv(NSLOT * 256 * HW, 256), 256, 0, stream>>>(inputs, featB);

    dim3 dgrid(WD / 16, HD, NSLOT);
    const float4* paDef4  = (const float4*)paDef;
    const float4* paPred4 = (const float4*)paPred;
    const int PA_CONV = 589824 / 4;       // float4 units per (layout, conv)
    const int PA_L1_DEF = 3 * PA_CONV;
    const int PA_L1_PRED = 147456 / 4;

    // 3 chained deform layers: featB -> featA -> featB -> featA
    double* cur = featB;
    double* nxt = featA;
    for (int i = 0; i < 3; ++i) {
        fused_deform_d<256, 8, false><<<dgrid, 256, 0, stream>>>(
            cur, owt + (size_t)i * 256 * 180, nullptr,
            paDef4 + (size_t)i * PA_CONV, PA_L1_DEF,
            wtdef + (size_t)i * 589824, nxt, 256);
        double* tmp = cur; cur = nxt; nxt = tmp;
    }
    // cur = featA; featB is dead -> reuse for outputs
    double* deform = featB;
    double* s1     = featB + (size_t)NSLOT * 128 * HW;
    double* s2     = s1    + (size_t)NSLOT * 64 * HW;
    double* wbuf   = s2    + (size_t)NSLOT * 32 * HW;

    fused_deform_d<128, 4, true><<<dgrid, 128, 0, stream>>>(
        cur, owt + (size_t)3 * 256 * 180, inputs, paPred4, PA_L1_PRED,
        wtpred, deform, 128);

    conv3x3_s4_d<<<cdiv(NSLOT * 16 * HW, 256), 256, 0, stream>>>(
        deform, s_w[0], s1, 128, 64, 1);
    conv3x3_s4_d<<<cdiv(NSLOT * 8 * HW, 256), 256, 0, stream>>>(
        s1, s_w[1], s2, 64, 32, 1);
    conv3x3_direct_d<<<cdiv(NSLOT * 1 * HW, 256), 256, 0, stream>>>(
        s2, s_w[2], wbuf, 32, 1, 1);

    fuse_d<<<cdiv(BATCH * 128 * HW, 256), 256, 0, stream>>>(deform, wbuf, out);
}

// Round 15
// 2372.869 us; speedup vs baseline: 7.5040x; 7.5040x over previous
//
#include <hip/hip_runtime.h>
#include <type_traits>

#define HD 64
#define WD 64
#define HW 4096
#define BATCH 2
#define NSLOT 4   // (branch, batch) merged slots: s = br*2 + b

typedef double v4d __attribute__((ext_vector_type(4)));
typedef double d2t __attribute__((ext_vector_type(2)));
typedef d2t d2u __attribute__((aligned(8)));      // unaligned-capable double2
typedef float f2t __attribute__((ext_vector_type(2)));
typedef f2t f2u __attribute__((aligned(4)));      // unaligned-capable float2

// ---- packed A-operand tables, BOTH candidate MFMA layouts ----
__global__ void pack_a_def_k(const float* __restrict__ w0, const float* __restrict__ w1,
                             const float* __restrict__ w2, float* __restrict__ pa) {
    int idx = blockIdx.x * 256 + threadIdx.x;
    if (idx >= 2 * 3 * 4 * 576 * 64 * 4) return;
    int tl = idx & 3;
    int l  = (idx >> 2) & 63;
    int m  = (idx >> 8) % 576;
    int rest = (idx >> 8) / 576;     // (L*3+conv)*4+wv
    int wv = rest & 3;
    int Lc = rest >> 2;
    int conv = Lc % 3, L = Lc / 3;
    int a_i = L ? (l >> 2) : (l & 15);
    int a_k = L ? (l & 3)  : (l >> 4);
    int kk = 4 * m + a_k;
    int c = kk / 9, k = kk % 9;
    int o = wv * 64 + tl * 16 + a_i;
    const float* w = (conv == 0) ? w0 : (conv == 1) ? w1 : w2;
    pa[idx] = w[((size_t)o * 256 + c) * 9 + k];
}

__global__ void pack_a_pred_k(const float* __restrict__ w, float* __restrict__ pa) {
    int idx = blockIdx.x * 256 + threadIdx.x;
    if (idx >= 2 * 2 * 288 * 64 * 4) return;
    int tl = idx & 3;
    int l  = (idx >> 2) & 63;
    int m  = (idx >> 8) % 288;
    int rest = (idx >> 8) / 288;     // L*2+wv
    int wv = rest & 1, L = rest >> 1;
    int a_i = L ? (l >> 2) : (l & 15);
    int a_k = L ? (l & 3)  : (l >> 4);
    int kk = 4 * m + a_k;
    int c = kk / 9, k = kk % 9;
    int o = wv * 64 + tl * 16 + a_i;
    pa[idx] = w[((size_t)o * 128 + c) * 9 + k];
}

// ---- merged offset-weight transpose: w[o][c][kk] -> owt[which][c][kk][20] ---
__global__ void transpose_ow4_k(const float* __restrict__ w0, const float* __restrict__ w1,
                                const float* __restrict__ w2, const float* __restrict__ w3,
                                float* __restrict__ owt) {
    const int N = 256 * 180;
    int idx = blockIdx.x * 256 + threadIdx.x;
    if (idx >= 4 * N) return;
    int which = idx / N, r = idx % N;
    const float* w = (which == 0) ? w0 : (which == 1) ? w1 : (which == 2) ? w2 : w3;
    int k20 = r % 20;
    int kk  = (r / 20) % 9;
    int c   = r / 180;
    owt[idx] = (k20 < 18) ? w[((size_t)k20 * 256 + c) * 9 + kk] : 0.f;
}

// ---- pack 4 slots: slot s=br*2+b, c<128 -> img 2b+br ; c>=128 -> img 2b+1 ---
__global__ void pack_feat4_d(const float* __restrict__ in, double* __restrict__ dst) {
    int idx = blockIdx.x * 256 + threadIdx.x;
    if (idx >= NSLOT * 256 * HW) return;
    int i = idx % HW;
    int c = (idx / HW) & 255;
    int s = idx / (256 * HW);
    int b = s & 1, br = s >> 1;
    int img = (c < 128) ? (2 * b + br) : (2 * b + 1);
    dst[idx] = (double)in[((size_t)(img * 128 + (c & 127))) * HW + i];
}

// ---- runtime-probe the f64 MFMA fragment layout ----
__device__ __forceinline__ void probe_mfma_f64(
    int lane, int& aL1, int& b_k, int& b_j, int row_map[4], int col_map[4]) {
    v4d z = {0.0, 0.0, 0.0, 0.0};
    v4d pA = __builtin_amdgcn_mfma_f64_16x16x4f64((double)lane, 1.0, z, 0, 0, 0);
    v4d pB = __builtin_amdgcn_mfma_f64_16x16x4f64(1.0, (double)lane, z, 0, 0, 0);
    int vA = (int)pA[0];
    aL1 = ((vA & 3) != 0);
    int vB = (int)pB[0];
    if ((vB & 3) == 0) { b_j = lane & 15; b_k = lane >> 4; }
    else               { b_j = lane >> 2; b_k = lane & 3; }
#pragma unroll
    for (int r = 0; r < 4; ++r) {
        int va = (int)pA[r];
        row_map[r] = ((va & 3) == 0) ? (va - 96) >> 2 : (va - 6) >> 4;
        int vb = (int)pB[r];
        col_map[r] = ((vb & 3) == 0) ? (vb - 96) >> 2 : (vb - 6) >> 4;
    }
}

// ---------------- FUSED offset-conv + deformable GEMM (MFMA f64) -------------
// Grid (4, HD, NSLOT); block O threads (O/64 waves).
template <int O, int CC, bool PRED>
__global__ __launch_bounds__(O) void fused_deform_d(
    const double* __restrict__ csrc,            // (NSLOT,256,HW) offset source
    const float*  __restrict__ owt,             // [c][kk][20]
    const float*  __restrict__ fsrc,            // raw inputs (PRED only)
    const float4* __restrict__ pa,              // packed A, layout0 base
    int paL1off,                                // float4 units to layout1
    double* __restrict__ dst, int Ci) {
    constexpr int NCGT = O / 16;
    constexpr int CPG  = 256 / NCGT;
    constexpr int KC   = CC * 9;
    constexpr int NELEM = CC * 144;
    constexpr int NR   = NELEM / O;
    constexpr int REM  = NELEM % O;
    constexpr int NG   = CC;
    static_assert(2 * KC * 17 >= NG * 288, "phase-0 scratch");
    static_assert(NCGT % NG == 0, "phase-0 rounds");
    static_assert(KC % 4 == 0, "K steps");

    int px0 = blockIdx.x * 16;
    int h   = blockIdx.y;
    int s   = blockIdx.z;
    int t   = threadIdx.x;

    __shared__ double s_samp[2][KC * 17];       // dbuf; also ph0 scratch
    __shared__ int    s_addr2[9][16][2];        // row bases (element offsets)
    __shared__ double s_w4[9][16][4];           // {cax, cay, wy0v, wy1v}
    __shared__ double s_off[18][16];

    // ---- phase 0: offset conv ----
    {
        int px = t & 15, cg = t >> 4;
        int gx = px0 + px;
        double part[18];
#pragma unroll
        for (int k = 0; k < 18; ++k) part[k] = 0.0;
        const double* fb = csrc + (size_t)s * 256 * HW;
        bool ym = (h > 0), yp = (h < HD - 1), xm = (gx > 0), xp = (gx < WD - 1);
        for (int cc = 0; cc < CPG; ++cc) {
            int c = cg * CPG + cc;
            const double* fc = fb + (size_t)c * HW + h * WD + gx;
            double v[9];
            v[0] = (ym && xm) ? fc[-WD - 1] : 0.0;
            v[1] = ym ? fc[-WD] : 0.0;
            v[2] = (ym && xp) ? fc[-WD + 1] : 0.0;
            v[3] = xm ? fc[-1] : 0.0;
            v[4] = fc[0];
            v[5] = xp ? fc[1] : 0.0;
            v[6] = (yp && xm) ? fc[WD - 1] : 0.0;
            v[7] = yp ? fc[WD] : 0.0;
            v[8] = (yp && xp) ? fc[WD + 1] : 0.0;
            const float* wr = owt + (size_t)c * 180;
#pragma unroll
            for (int kk = 0; kk < 9; ++kk) {
                float wl[20];
                ((float4*)wl)[0] = *(const float4*)(wr + kk * 20);
                ((float4*)wl)[1] = *(const float4*)(wr + kk * 20 + 4);
                ((float4*)wl)[2] = *(const float4*)(wr + kk * 20 + 8);
                ((float4*)wl)[3] = *(const float4*)(wr + kk * 20 + 12);
                ((float4*)wl)[4] = *(const float4*)(wr + kk * 20 + 16);
                double vv = v[kk];
#pragma unroll
                for (int k = 0; k < 18; ++k)
                    part[k] = fma(vv, (double)wl[k], part[k]);
            }
        }
        double* s_part = &s_samp[0][0];
        for (int r0 = 0; r0 < NCGT; r0 += NG) {
            if (cg >= r0 && cg < r0 + NG) {
#pragma unroll
                for (int k = 0; k < 18; ++k)
                    s_part[((size_t)(cg - r0) * 18 + k) * 16 + px] = part[k];
            }
            __syncthreads();
            for (int i = t; i < 288; i += O) {
                int k = i >> 4, p2 = i & 15;
                double ssum = 0.0;
                for (int g = 0; g < NG; ++g)
                    ssum += s_part[((size_t)g * 18 + k) * 16 + p2];
                if (r0 == 0) s_off[k][p2] = ssum;
                else         s_off[k][p2] += ssum;
            }
            __syncthreads();
        }
    }

    // ---- phase 1: sampling positions -> paired-row bases + eff. weights ----
    for (int i = t; i < 144; i += O) {
        int k = i / 16, px = i % 16, wc = px0 + px;
        double dy = s_off[2 * k][px];
        double dx = s_off[2 * k + 1][px];
        double py  = dy + (double)(k / 3 - 1 + h);
        double pxf = dx + (double)(k % 3 - 1 + wc);
        double y0f = floor(py), x0f = floor(pxf);
        double wy1 = py - y0f, wx1 = pxf - x0f;
        double wy0 = 1.0 - wy1, wx0 = 1.0 - wx1;
        double y0c = fmax(-2.0, fmin(66.0, y0f));
        double x0c = fmax(-2.0, fmin(66.0, x0f));
        int y0 = (int)y0c, x0 = (int)x0c;
        int y1 = y0 + 1,   x1 = x0 + 1;
        bool vy0 = (y0 >= 0 && y0 < HD), vy1 = (y1 >= 0 && y1 < HD);
        bool vx0 = (x0 >= 0 && x0 < WD), vx1 = (x1 >= 0 && x1 < WD);
        int yc0 = min(max(y0, 0), HD - 1), yc1 = min(max(y1, 0), HD - 1);
        int xbase = min(max(x0, 0), WD - 2);
        s_addr2[k][px][0] = yc0 * WD + xbase;
        s_addr2[k][px][1] = yc1 * WD + xbase;
        bool sel0 = (x0 >= WD - 1);   // corner x0 uses .y
        bool sel1 = (x0 >= 0);        // corner x1 uses .y
        double wx0v = vx0 ? wx0 : 0.0;
        double wx1v = vx1 ? wx1 : 0.0;
        s_w4[k][px][0] = (sel0 ? 0.0 : wx0v) + (sel1 ? 0.0 : wx1v);  // cax
        s_w4[k][px][1] = (sel0 ? wx0v : 0.0) + (sel1 ? wx1v : 0.0);  // cay
        s_w4[k][px][2] = vy0 ? wy0 : 0.0;
        s_w4[k][px][3] = vy1 ? wy1 : 0.0;
    }
    __syncthreads();

    // ---- phase 2: double-buffered paired staging + MFMA-f64 GEMM -----------
    int b = s & 1, br = s >> 1;
    const double* srcb_d = csrc + (size_t)s * 256 * HW;
    const float*  srcb_f = PRED ? (fsrc + (size_t)(2 * b + br) * 128 * HW) : nullptr;

    using PairT = typename std::conditional<PRED, f2u, d2u>::type;
    PairT rp0[NR + 1], rp1[NR + 1];

    auto stage_issue = [&](int c0) {
#pragma unroll
        for (int n = 0; n <= NR; ++n) {
            if (n == NR && (REM == 0 || t >= REM)) continue;
            int i = t + n * O;
            int px = i & 15, kk = (i >> 4) % 9, c = i / 144;
            int a0 = s_addr2[kk][px][0], a1 = s_addr2[kk][px][1];
            if constexpr (PRED) {
                const float* p = srcb_f + (size_t)(c0 + c) * HW;
                rp0[n] = *(const f2u*)(p + a0);
                rp1[n] = *(const f2u*)(p + a1);
            } else {
                const double* p = srcb_d + (size_t)(c0 + c) * HW;
                rp0[n] = *(const d2u*)(p + a0);
                rp1[n] = *(const d2u*)(p + a1);
            }
        }
    };
    auto stage_finish = [&](int buf) {
#pragma unroll
        for (int n = 0; n <= NR; ++n) {
            if (n == NR && (REM == 0 || t >= REM)) continue;
            int i = t + n * O;
            int px = i & 15, kk = (i >> 4) % 9, c = i / 144;
            const double* wq = s_w4[kk][px];
            double r0 = (double)rp0[n].x * wq[0] + (double)rp0[n].y * wq[1];
            double r1 = (double)rp1[n].x * wq[0] + (double)rp1[n].y * wq[1];
            s_samp[buf][(c * 9 + kk) * 17 + px] = wq[2] * r0 + wq[3] * r1;
        }
    };

    int lane = t & 63;
    int wvid = t >> 6;
    int o0w  = wvid * 64;

    int aL1, b_k, b_j;
    int row_map[4], col_map[4];
    probe_mfma_f64(lane, aL1, b_k, b_j, row_map, col_map);

    size_t TOTM = (size_t)Ci * 9 / 4;
    const float4* wp0 = pa + (aL1 ? (size_t)paL1off : 0)
                      + (size_t)wvid * TOTM * 64 + lane;

    v4d acc[4];
#pragma unroll
    for (int tl = 0; tl < 4; ++tl) acc[tl] = (v4d){0.0, 0.0, 0.0, 0.0};

    stage_issue(0);
    stage_finish(0);
    __syncthreads();

    const int nch = Ci / CC;
    for (int ch = 0; ch < nch; ++ch) {
        int cur = ch & 1;
        bool more = (ch + 1 < nch);
        if (more) stage_issue((ch + 1) * CC);
        {
            const double* sb = &s_samp[cur][0];
            const float4* wp = wp0 + (size_t)ch * (KC / 4) * 64;
#pragma unroll
            for (int m = 0; m < KC / 4; ++m) {
                float4 av = wp[(size_t)m * 64];
                double bval = sb[(4 * m + b_k) * 17 + b_j];
                acc[0] = __builtin_amdgcn_mfma_f64_16x16x4f64((double)av.x, bval, acc[0], 0, 0, 0);
                acc[1] = __builtin_amdgcn_mfma_f64_16x16x4f64((double)av.y, bval, acc[1], 0, 0, 0);
                acc[2] = __builtin_amdgcn_mfma_f64_16x16x4f64((double)av.z, bval, acc[2], 0, 0, 0);
                acc[3] = __builtin_amdgcn_mfma_f64_16x16x4f64((double)av.w, bval, acc[3], 0, 0, 0);
            }
        }
        if (more) stage_finish(cur ^ 1);
        __syncthreads();
    }
#pragma unroll
    for (int tl = 0; tl < 4; ++tl) {
#pragma unroll
        for (int r = 0; r < 4; ++r) {
            int o = o0w + tl * 16 + row_map[r];
            dst[((size_t)(s * O + o) * HD + h) * WD + px0 + col_map[r]] = acc[tl][r];
        }
    }
}

// ---------------- S-net conv3x3: 4 outputs per thread, fp64 ------------------
__global__ __launch_bounds__(256) void conv3x3_s4_d(
    const double* __restrict__ src, const float* __restrict__ w,
    double* __restrict__ dst, int Ci, int O, int relu) {
    int idx = blockIdx.x * 256 + threadIdx.x;
    int px   = idx & 4095;
    int rest = idx >> 12;
    int og   = rest % (O >> 2);
    int img  = rest / (O >> 2);
    if (img >= NSLOT) return;
    int x = px & 63, h = px >> 6;
    const double* sb = src + (size_t)img * Ci * HW + h * WD + x;
    bool ym = (h > 0), yp = (h < HD - 1), xm = (x > 0), xp = (x < WD - 1);
    double acc[4] = {0.0, 0.0, 0.0, 0.0};
    for (int c = 0; c < Ci; ++c) {
        const double* sc = sb + (size_t)c * HW;
        double v[9];
        v[0] = (ym && xm) ? sc[-WD - 1] : 0.0;
        v[1] = ym ? sc[-WD] : 0.0;
        v[2] = (ym && xp) ? sc[-WD + 1] : 0.0;
        v[3] = xm ? sc[-1] : 0.0;
        v[4] = sc[0];
        v[5] = xp ? sc[1] : 0.0;
        v[6] = (yp && xm) ? sc[WD - 1] : 0.0;
        v[7] = yp ? sc[WD] : 0.0;
        v[8] = (yp && xp) ? sc[WD + 1] : 0.0;
#pragma unroll
        for (int oi = 0; oi < 4; ++oi) {
            const float* wc = w + ((size_t)(og * 4 + oi) * Ci + c) * 9;
#pragma unroll
            for (int k = 0; k < 9; ++k)
                acc[oi] = fma(v[k], (double)wc[k], acc[oi]);
        }
    }
#pragma unroll
    for (int oi = 0; oi < 4; ++oi) {
        double vv = acc[oi];
        if (relu) vv = fmax(vv, 0.0);
        dst[((size_t)(img * O + og * 4 + oi)) * HW + px] = vv;
    }
}

// ---------------- direct conv3x3 (final O=1 S-conv), 4 imgs ------------------
__global__ __launch_bounds__(256) void conv3x3_direct_d(
    const double* __restrict__ src, const float* __restrict__ w,
    double* __restrict__ dst, int Ci, int O, int relu) {
    int idx = blockIdx.x * 256 + threadIdx.x;
    int total = NSLOT * O * HW;
    if (idx >= total) return;
    int x = idx & (WD - 1);
    int h = (idx >> 6) & (HD - 1);
    int rest = idx >> 12;
    int o = rest % O;
    int img = rest / O;
    const double* s  = src + (size_t)img * Ci * HW + h * WD + x;
    const float*  wo = w + (size_t)o * Ci * 9;
    bool ym = (h > 0), yp = (h < HD - 1), xm = (x > 0), xp = (x < WD - 1);
    double a0 = 0.0, a1 = 0.0, a2 = 0.0;
    for (int c = 0; c < Ci; ++c) {
        const double* sc = s + (size_t)c * HW;
        const float*  wc = wo + c * 9;
        if (ym) {
            double v0 = xm ? sc[-WD - 1] : 0.0;
            double v1 = sc[-WD];
            double v2 = xp ? sc[-WD + 1] : 0.0;
            a0 = fma(v0, (double)wc[0], a0);
            a0 = fma(v1, (double)wc[1], a0);
            a0 = fma(v2, (double)wc[2], a0);
        }
        {
            double v0 = xm ? sc[-1] : 0.0;
            double v1 = sc[0];
            double v2 = xp ? sc[1] : 0.0;
            a1 = fma(v0, (double)wc[3], a1);
            a1 = fma(v1, (double)wc[4], a1);
            a1 = fma(v2, (double)wc[5], a1);
        }
        if (yp) {
            double v0 = xm ? sc[WD - 1] : 0.0;
            double v1 = sc[WD];
            double v2 = xp ? sc[WD + 1] : 0.0;
            a2 = fma(v0, (double)wc[6], a2);
            a2 = fma(v1, (double)wc[7], a2);
            a2 = fma(v2, (double)wc[8], a2);
        }
    }
    double acc = (a0 + a1) + a2;
    if (relu) acc = fmax(acc, 0.0);
    dst[idx] = acc;
}

// ---------------- fusion: cos-sim -> softmax -> blend, fp64 ------------------
__global__ void fuse_d(const double* __restrict__ dfm,   // (4,128,HW)
                       const double* __restrict__ wbuf,  // (4,HW)
                       float* __restrict__ out) {
    int idx = blockIdx.x * 256 + threadIdx.x;
    if (idx >= BATCH * 128 * HW) return;
    int i = idx % HW;
    int b = idx / (128 * HW);
    double a  = wbuf[(size_t)b * HW + i];
    double bb = wbuf[(size_t)(2 + b) * HW + i];
    double Wx = (a * bb) / sqrt(fmax((a * a) * (bb * bb), 1e-16));
    double Wy = (bb * bb) / sqrt(fmax((bb * bb) * (bb * bb), 1e-16));
    double m  = fmax(Wx, Wy);
    double e0 = exp(Wx - m), e1 = exp(Wy - m);
    double inv = 1.0 / (e0 + e1);
    double d0 = dfm[idx];
    double d1 = dfm[(size_t)2 * 128 * HW + idx];
    out[idx] = (float)((d0 * e0 + d1 * e1) * inv);
}

// ---------------- launch -----------------------------------------------------
extern "C" void kernel_launch(void* const* d_in, const int* in_sizes, int n_in,
                              void* d_out, int out_size, void* d_ws, size_t ws_size,
                              hipStream_t stream) {
    const float* inputs = (const float*)d_in[2];
    const float* off_w[4] = {(const float*)d_in[3], (const float*)d_in[4],
                             (const float*)d_in[5], (const float*)d_in[6]};
    const float* def_w[3] = {(const float*)d_in[7], (const float*)d_in[8],
                             (const float*)d_in[9]};
    const float* pred_w = (const float*)d_in[10];
    const float* s_w[3] = {(const float*)d_in[11], (const float*)d_in[12],
                           (const float*)d_in[13]};
    float* out = (float*)d_out;

    // workspace (double units; all sub-arrays even-double => 16B aligned)
    double* ws = (double*)d_ws;
    size_t o = 0;
    double* featA = ws + o; o += (size_t)NSLOT * 256 * HW;
    double* featB = ws + o; o += (size_t)NSLOT * 256 * HW;
    float* owt    = (float*)(ws + o); o += (size_t)4 * 256 * 180 / 2;
    float* paDef  = (float*)(ws + o); o += (size_t)2 * 3 * 589824 / 2;
    float* paPred = (float*)(ws + o); o += (size_t)2 * 147456 / 2;
    if (ws_size < o * sizeof(double)) return;

    auto cdiv = [](int a, int b) { return (a + b - 1) / b; };

    pack_a_def_k<<<cdiv(2 * 3 * 589824, 256), 256, 0, stream>>>(
        def_w[0], def_w[1], def_w[2], paDef);
    pack_a_pred_k<<<cdiv(2 * 147456, 256), 256, 0, stream>>>(pred_w, paPred);
    transpose_ow4_k<<<cdiv(4 * 256 * 180, 256), 256, 0, stream>>>(
        off_w[0], off_w[1], off_w[2], off_w[3], owt);

    pack_feat4_d<<<cdiv(NSLOT * 256 * HW, 256), 256, 0, stream>>>(inputs, featB);

    dim3 dgrid(WD / 16, HD, NSLOT);
    const float4* paDef4  = (const float4*)paDef;
    const float4* paPred4 = (const float4*)paPred;
    const int PA_CONV = 589824 / 4;       // float4 units per (layout, conv)
    const int PA_L1_DEF = 3 * PA_CONV;
    const int PA_L1_PRED = 147456 / 4;

    // 3 chained deform layers: featB -> featA -> featB -> featA
    double* cur = featB;
    double* nxt = featA;
    for (int i = 0; i < 3; ++i) {
        fused_deform_d<256, 8, false><<<dgrid, 256, 0, stream>>>(
            cur, owt + (size_t)i * 256 * 180, nullptr,
            paDef4 + (size_t)i * PA_CONV, PA_L1_DEF, nxt, 256);
        double* tmp = cur; cur = nxt; nxt = tmp;
    }
    // cur = featA; featB is dead -> reuse for outputs
    double* deform = featB;
    double* s1     = featB + (size_t)NSLOT * 128 * HW;
    double* s2     = s1    + (size_t)NSLOT * 64 * HW;
    double* wbuf   = s2    + (size_t)NSLOT * 32 * HW;

    fused_deform_d<128, 8, true><<<dgrid, 128, 0, stream>>>(
        cur, owt + (size_t)3 * 256 * 180, inputs, paPred4, PA_L1_PRED, deform, 128);

    conv3x3_s4_d<<<cdiv(NSLOT * 16 * HW, 256), 256, 0, stream>>>(
        deform, s_w[0], s1, 128, 64, 1);
    conv3x3_s4_d<<<cdiv(NSLOT * 8 * HW, 256), 256, 0, stream>>>(
        s1, s_w[1], s2, 64, 32, 1);
    conv3x3_direct_d<<<cdiv(NSLOT * 1 * HW, 256), 256, 0, stream>>>(
        s2, s_w[2], wbuf, 32, 1, 1);

    fuse_d<<<cdiv(BATCH * 128 * HW, 256), 256, 0, stream>>>(deform, wbuf, out);
}